// Round 1
// baseline (237.699 us; speedup 1.0000x reference)
//
#include <hip/hip_runtime.h>
#include <hip/hip_bf16.h>

// Problem constants (fixed by setup_inputs)
#define BATCH 32
#define LSEQ 1025
#define TT 2048
#define NTOK 513     // 1 + (LSEQ-1)/2
#define EMB 384
#define INV_SQRT_2PI 0.3989422804014327f

// ---------------------------------------------------------------------------
// Kernel 1: merge blank/token pairs, cumsum durations, emit per-token
// center c, width sig, token id, and per-batch total duration.
// One block per batch row; N=513 is tiny so a serial scan by thread 0 is fine.
// ---------------------------------------------------------------------------
__global__ __launch_bounds__(64) void prep_kernel(
    const int* __restrict__ text, const int* __restrict__ durs,
    float* __restrict__ c_arr, float* __restrict__ sig_arr,
    int* __restrict__ tok_arr, float* __restrict__ total_arr) {
  const int b = blockIdx.x;
  const int tid = threadIdx.x;
  __shared__ float s_d[NTOK];
  __shared__ float s_cum[NTOK];
  const int* tb = text + b * LSEQ;
  const int* db = durs + b * LSEQ;
  for (int n = tid; n < NTOK; n += 64) {
    int dm, tk;
    if (n == 0) {
      dm = db[0];
      tk = tb[0];
    } else {
      dm = db[2 * n - 1] + db[2 * n];  // durs[:,1::2] + durs[:,2::2]
      tk = tb[2 * n - 1];              // text[:,1::2]
    }
    s_d[n] = (float)dm;
    tok_arr[b * NTOK + n] = tk;
  }
  __syncthreads();
  if (tid == 0) {
    float cum = 0.f;
    for (int n = 0; n < NTOK; ++n) {  // small-int cumsum: exact in fp32
      cum += s_d[n];
      s_cum[n] = cum;
    }
    total_arr[b] = cum;
  }
  __syncthreads();
  for (int n = tid; n < NTOK; n += 64) {
    float d = s_d[n];
    c_arr[b * NTOK + n] = s_cum[n] - 0.5f * d;     // token center
    sig_arr[b * NTOK + n] = 0.5f * d + 1e-6f;      // d/SIGMA_C + EPS
  }
}

// ---------------------------------------------------------------------------
// Kernel 2: one block per (b, t). Compute all 513 Gaussian weights, compact
// the (exactly-)nonzero ones into LDS (~15 on average: fp32 exp underflow
// matches the reference's fp32 underflow), reduce their sum, then each of the
// 384 threads mixes one embedding column over the compacted set and writes
// one coalesced output row.
// ---------------------------------------------------------------------------
__global__ __launch_bounds__(384) void frames_kernel(
    const float* __restrict__ c_arr, const float* __restrict__ sig_arr,
    const int* __restrict__ tok_arr, const float* __restrict__ total_arr,
    const float* __restrict__ emb, float* __restrict__ out) {
  const int t = blockIdx.x;
  const int b = blockIdx.y;
  const int tid = threadIdx.x;

  __shared__ float s_w[NTOK];   // worst case: all tokens active
  __shared__ int s_off[NTOK];   // precomputed row offsets tok*EMB
  __shared__ int s_cnt;
  __shared__ float s_sum;
  if (tid == 0) {
    s_cnt = 0;
    s_sum = 0.f;
  }
  __syncthreads();

  const float tf = (float)t + 0.5f;
  float psum = 0.f;
  for (int n = tid; n < NTOK; n += 384) {
    const int base = b * NTOK + n;
    const float cc = c_arr[base];
    const float sg = sig_arr[base];
    const int tk = tok_arr[base];
    const float z = (tf - cc) / sg;
    float w = __expf(-0.5f * z * z) * (INV_SQRT_2PI / sg);
    if (tk == 0) w = 0.f;  // PAD mask
    if (w > 0.f) {
      const int slot = atomicAdd(&s_cnt, 1);
      s_w[slot] = w;
      s_off[slot] = tk * EMB;
      psum += w;
    }
  }
  // block reduction of the weight sum: wave shuffle, then one LDS atomic/wave
  for (int off = 32; off > 0; off >>= 1) psum += __shfl_down(psum, off);
  if ((tid & 63) == 0 && psum != 0.f) atomicAdd(&s_sum, psum);
  __syncthreads();

  const int cnt = s_cnt;
  const float r = 1.0f / (s_sum + 1e-6f);
  const bool valid = tf < total_arr[b];

  float acc = 0.f;
  for (int j = 0; j < cnt; ++j) {
    acc += s_w[j] * emb[s_off[j] + tid];  // broadcast LDS + coalesced gather
  }
  const size_t oidx = ((size_t)b * TT + t) * EMB + tid;
  out[oidx] = valid ? acc * r : 0.f;
}

extern "C" void kernel_launch(void* const* d_in, const int* in_sizes, int n_in,
                              void* d_out, int out_size, void* d_ws,
                              size_t ws_size, hipStream_t stream) {
  const int* text = (const int*)d_in[0];
  const int* durs = (const int*)d_in[1];
  const float* emb = (const float*)d_in[2];
  // d_in[3] = total_time (2048), fixed by the problem; TT is hardcoded.
  float* out = (float*)d_out;

  // workspace layout (~197 KB): c | sig | total | tok
  float* c_arr = (float*)d_ws;
  float* sig_arr = c_arr + BATCH * NTOK;
  float* total_arr = sig_arr + BATCH * NTOK;
  int* tok_arr = (int*)(total_arr + BATCH);

  prep_kernel<<<BATCH, 64, 0, stream>>>(text, durs, c_arr, sig_arr, tok_arr,
                                        total_arr);
  frames_kernel<<<dim3(TT, BATCH), 384, 0, stream>>>(c_arr, sig_arr, tok_arr,
                                                     total_arr, emb, out);
}

// Round 2
// 133.548 us; speedup vs baseline: 1.7799x; 1.7799x over previous
//
#include <hip/hip_runtime.h>
#include <hip/hip_bf16.h>

// Problem constants (fixed by setup_inputs)
#define BATCH 32
#define LSEQ 1025
#define TT 2048
#define NTOK 513      // 1 + (LSEQ-1)/2
#define EMB 384
#define FT 32         // frames per tile
#define WMAX 120      // hard bound: kept tokens are >=1 frame apart; window span ~112
#define INV_SQRT_2PI 0.3989422804014327f

// ---------------------------------------------------------------------------
// Inclusive Hillis-Steele scan over NTOK elements with 256 threads.
// src/dst are LDS ping-pong buffers; returns the buffer holding the result.
// Caller must __syncthreads() after filling src.
// ---------------------------------------------------------------------------
__device__ inline float* scan513(float* src, float* dst) {
  for (int off = 1; off < NTOK; off <<= 1) {
    for (int i = threadIdx.x; i < NTOK; i += 256) {
      float v = src[i];
      if (i >= off) v += src[i - off];
      dst[i] = v;
    }
    __syncthreads();
    float* t = src; src = dst; dst = t;
  }
  return src;  // result lives here after the final swap
}

// ---------------------------------------------------------------------------
// prep: merge blank/token pairs, parallel cumsum, filter tokens that can ever
// have nonzero weight (d>=1 && tok!=PAD; d=0 underflows exactly: centers are
// int/half-int, frame midpoints x.5 -> |z|>=5e5), ordered compaction into
// 8-byte records {c, (d<<17)|tok*EMB}. Also per-batch kept count and total.
// ---------------------------------------------------------------------------
__global__ __launch_bounds__(256) void prep_kernel(
    const int* __restrict__ text, const int* __restrict__ durs,
    float2* __restrict__ kept, int* __restrict__ counts,
    float* __restrict__ totals) {
  const int b = blockIdx.x;
  const int tid = threadIdx.x;
  __shared__ float s_a[NTOK], s_b[NTOK];   // scan ping-pong
  __shared__ float s_c[NTOK];              // token centers
  __shared__ float s_d[NTOK];              // merged durations
  __shared__ int s_tok[NTOK];

  const int* tb = text + b * LSEQ;
  const int* db = durs + b * LSEQ;
  for (int n = tid; n < NTOK; n += 256) {
    int dm, tk;
    if (n == 0) { dm = db[0]; tk = tb[0]; }
    else { dm = db[2 * n - 1] + db[2 * n]; tk = tb[2 * n - 1]; }
    s_d[n] = (float)dm;
    s_a[n] = (float)dm;
    s_tok[n] = tk;
  }
  __syncthreads();
  float* cum = scan513(s_a, s_b);          // inclusive cumsum (exact: small ints)
  for (int n = tid; n < NTOK; n += 256) {
    s_c[n] = cum[n] - 0.5f * s_d[n];       // token center
  }
  if (tid == 0) totals[b] = cum[NTOK - 1];
  __syncthreads();
  // keep flags -> ordered compaction positions
  float* flagbuf = (cum == s_a) ? s_a : s_b;  // reuse whichever holds cum
  float* other = (cum == s_a) ? s_b : s_a;
  for (int n = tid; n < NTOK; n += 256) {
    flagbuf[n] = (s_d[n] >= 1.0f && s_tok[n] != 0) ? 1.0f : 0.0f;
  }
  __syncthreads();
  // stash flags in s_d's place? need d later; scan in ping-pong (destroys cum, ok)
  float* incl = scan513(flagbuf, other);
  for (int n = tid; n < NTOK; n += 256) {
    float d = s_d[n];
    int tk = s_tok[n];
    if (d >= 1.0f && tk != 0) {
      int pos = (int)incl[n] - 1;
      int packed = ((int)d << 17) | (tk * EMB);
      kept[b * NTOK + pos] = make_float2(s_c[n], __int_as_float(packed));
    }
  }
  if (tid == 0) counts[b] = (int)incl[NTOK - 1];
}

// ---------------------------------------------------------------------------
// frames: one block per (batch, 32-frame tile). 192 threads.
// 1) binary-search the kept-token window relevant to this tile
// 2) stage token params to LDS, eval dense weight matrix [win][32] into LDS
// 3) per-frame sums -> normalization factor (0 beyond total duration)
// 4) token-major mix: thread owns 4 cols x 16 frames; each embedding row is
//    loaded once per half-tile (not once per frame)
// ---------------------------------------------------------------------------
__global__ __launch_bounds__(192) void frames_kernel(
    const float2* __restrict__ kept, const int* __restrict__ counts,
    const float* __restrict__ totals, const float* __restrict__ emb,
    float* __restrict__ out) {
  const int t0 = blockIdx.x * FT;
  const int b = blockIdx.y;
  const int tid = threadIdx.x;

  __shared__ float4 s_tk[WMAX];     // {c, inv_sig, coef, off bitcast}
  __shared__ float s_reach[WMAX];   // 6.7*d (+eps): covers 13.22*sig cutoff
  __shared__ float s_w[WMAX * FT];
  __shared__ float s_factor[FT];

  const int M = counts[b];
  const float total = totals[b];
  const float2* kb = kept + b * NTOK;

  // window: tokens with c in [t0-39.5, t0+71.5] (reach <= 39.7)
  const float loB = (float)t0 - 39.5f;
  const float hiB = (float)t0 + (float)(FT - 1) + 40.5f;
  int l = 0, r = M;
  while (l < r) { int m = (l + r) >> 1; if (kb[m].x < loB) l = m + 1; else r = m; }
  const int lo = l;
  r = M;
  while (l < r) { int m = (l + r) >> 1; if (kb[m].x <= hiB) l = m + 1; else r = m; }
  int win = l - lo;
  if (win > WMAX) win = WMAX;  // unreachable for valid inputs (hard bound 113)

  // stage token params
  for (int i = tid; i < win; i += 192) {
    float2 kv = kb[lo + i];
    int packed = __float_as_int(kv.y);
    int d = packed >> 17;
    int off = packed & 0x1FFFF;
    float df = (float)d;
    float inv_sig = 1.0f / (0.5f * df + 1e-6f);  // matches ref sig exactly
    s_tk[i] = make_float4(kv.x, inv_sig, INV_SQRT_2PI * inv_sig,
                          __int_as_float(off));
    s_reach[i] = 6.7f * df + 1e-4f;
  }
  __syncthreads();

  // dense weight eval: one mul + one exp per (token, frame)
  const float t0f = (float)t0 + 0.5f;
  const int pairs = win * FT;
  for (int idx = tid; idx < pairs; idx += 192) {
    const int n = idx >> 5, f = idx & (FT - 1);
    const float4 tk = s_tk[n];
    const float z = (t0f + (float)f - tk.x) * tk.y;
    s_w[idx] = tk.z * __expf(-0.5f * z * z);
  }
  __syncthreads();

  // per-frame sums -> factor
  if (tid < FT) {
    float s = 0.f;
    for (int n = 0; n < win; ++n) s += s_w[n * FT + tid];
    const float tf = t0f + (float)tid;
    s_factor[tid] = (tf < total) ? 1.0f / (s + 1e-6f) : 0.0f;
  }
  __syncthreads();

  // mix: thread -> half-tile fh (16 frames) x 4 columns
  const int fh = tid / 96;
  const int cg = (tid % 96) * 4;
  const int fbase = fh * 16;
  float4 acc[16];
#pragma unroll
  for (int k = 0; k < 16; ++k) acc[k] = make_float4(0.f, 0.f, 0.f, 0.f);

  const float fLo = (float)(t0 + fbase) + 0.5f;
  const float fHi = fLo + 15.0f;
  for (int n = 0; n < win; ++n) {
    const float4 tk = s_tk[n];
    const float reach = s_reach[n];
    if (tk.x + reach < fLo || tk.x - reach > fHi) continue;  // uniform skip
    const int off = __float_as_int(tk.w);
    const float4 v = *(const float4*)(emb + off + cg);
    const float4* wp = (const float4*)(s_w + n * FT + fbase);
#pragma unroll
    for (int q = 0; q < 4; ++q) {
      const float4 w4 = wp[q];
      float4& a0 = acc[4 * q + 0];
      a0.x += w4.x * v.x; a0.y += w4.x * v.y; a0.z += w4.x * v.z; a0.w += w4.x * v.w;
      float4& a1 = acc[4 * q + 1];
      a1.x += w4.y * v.x; a1.y += w4.y * v.y; a1.z += w4.y * v.z; a1.w += w4.y * v.w;
      float4& a2 = acc[4 * q + 2];
      a2.x += w4.z * v.x; a2.y += w4.z * v.y; a2.z += w4.z * v.z; a2.w += w4.z * v.w;
      float4& a3 = acc[4 * q + 3];
      a3.x += w4.w * v.x; a3.y += w4.w * v.y; a3.z += w4.w * v.z; a3.w += w4.w * v.w;
    }
  }

  // normalize + write (covers every frame incl. invalid -> zeros)
  const size_t obase = ((size_t)b * TT + t0 + fbase) * EMB + cg;
#pragma unroll
  for (int k = 0; k < 16; ++k) {
    const float fac = s_factor[fbase + k];
    float4 r;
    r.x = acc[k].x * fac; r.y = acc[k].y * fac;
    r.z = acc[k].z * fac; r.w = acc[k].w * fac;
    *(float4*)(out + obase + (size_t)k * EMB) = r;
  }
}

extern "C" void kernel_launch(void* const* d_in, const int* in_sizes, int n_in,
                              void* d_out, int out_size, void* d_ws,
                              size_t ws_size, hipStream_t stream) {
  const int* text = (const int*)d_in[0];
  const int* durs = (const int*)d_in[1];
  const float* emb = (const float*)d_in[2];
  float* out = (float*)d_out;

  // workspace: kept float2[32*513] (131 KB) | counts int[32] | totals float[32]
  float2* kept = (float2*)d_ws;
  int* counts = (int*)(kept + BATCH * NTOK);
  float* totals = (float*)(counts + BATCH);

  prep_kernel<<<BATCH, 256, 0, stream>>>(text, durs, kept, counts, totals);
  frames_kernel<<<dim3(TT / FT, BATCH), 192, 0, stream>>>(kept, counts, totals,
                                                          emb, out);
}